// Round 13
// baseline (202.990 us; speedup 1.0000x reference)
//
#include <hip/hip_runtime.h>
#include <math.h>

// Problem dims
constexpr int B   = 16;
constexpr int K   = 64;
constexpr int BK  = B * K;        // 1024
constexpr int IN  = 128;
constexpr int H0  = 192;
constexpr int H1  = 64;
constexpr int UNF = 6;
constexpr float EPS = 1e-8f;
constexpr float DT  = 1.0f / 6.0f;
constexpr float L2E = 1.4426950408889634f;   // log2(e)

typedef float v2f __attribute__((ext_vector_type(2)));

static __device__ __forceinline__ float rcpf(float x) {
    return __builtin_amdgcn_rcpf(x);
}
static __device__ __forceinline__ float exp2_fast(float x) {
#if __has_builtin(__builtin_amdgcn_exp2f)
    return __builtin_amdgcn_exp2f(x);   // v_exp_f32
#else
    return exp2f(x);
#endif
}
// sigmoid(z) with z pre-scaled by log2(e): s = 1/(1+2^(-z2)); t = -z2
static __device__ __forceinline__ float sig_from_t(float t) {
    return rcpf(1.0f + exp2_fast(t));
}

// 4 rows of sigmoid-synapse accumulate for one (i,h) pack element.
// Rows paired as v2f (v_pk_{fma,add,min,mul}); the two rcp's of a pair are
// FUSED into one: s0 = rcp(a0*a1)*a1, s1 = rcp(a0*a1)*a0 where a_i = 1+2^t_i.
// t clamped at 62 so the pair product stays < 2^125 (no inf poisoning; a
// clamped t=62 gives s ~ 2^-62 ~ 0, indistinguishable from the exact value).
// Trans ops: 8 -> 6 per call (4 exp2 + 2 rcp); pk-VALU: 8 -> ~11.
static __device__ __forceinline__ void rows4pk(const float4 p, const float4 vv,
                                               v2f& n01, v2f& d01,
                                               v2f& n23, v2f& d23) {
    v2f v01; v01.x = vv.x; v01.y = vv.y;
    v2f v23; v23.x = vv.z; v23.y = vv.w;
    v2f t01 = p.z - p.y * v01;                // v_pk_fma_f32
    v2f t23 = p.z - p.y * v23;
    t01 = __builtin_elementwise_min(t01, (v2f)62.0f);   // v_pk_min_f32
    t23 = __builtin_elementwise_min(t23, (v2f)62.0f);
    v2f e01, e23;
    e01.x = exp2_fast(t01.x); e01.y = exp2_fast(t01.y);
    e23.x = exp2_fast(t23.x); e23.y = exp2_fast(t23.y);
    const v2f a01 = e01 + 1.0f;               // v_pk_add_f32
    const v2f a23 = e23 + 1.0f;
    const float r01 = rcpf(a01.x * a01.y);    // one rcp per row-pair
    const float r23 = rcpf(a23.x * a23.y);
    v2f s01; s01.x = r01 * a01.y; s01.y = r01 * a01.x;
    v2f s23; s23.x = r23 * a23.y; s23.y = r23 * a23.x;
    n01 += s01 * p.w;  d01 += s01 * p.x;      // v_pk_fma_f32 (splat)
    n23 += s23 * p.w;  d23 += s23 * p.x;
}

// ---------------------------------------------------------------------------
// Prep: (a) pack {relu(w), sig*L2E, sig*mu*L2E, relu(w)*erev} into float4 for
// the three hot matrices; (b) layer-0 input synapse sums [B,H0] (x is shared
// by all K particles and all 6 steps). One kernel, branch on blockIdx.
constexpr int NPACK    = H0 * H0 + H0 * H1 + H1 * H1;  // 53248
constexpr int NPACKBLK = NPACK / 256;                   // 208
__global__ __launch_bounds__(256) void prep_kernel(
    const float* __restrict__ w0,  const float* __restrict__ sig0,
    const float* __restrict__ mu0, const float* __restrict__ erev0,
    const float* __restrict__ iw1, const float* __restrict__ isig1,
    const float* __restrict__ imu1,const float* __restrict__ ierev1,
    const float* __restrict__ w1,  const float* __restrict__ sig1,
    const float* __restrict__ mu1, const float* __restrict__ erev1,
    const float* __restrict__ x,   const float* __restrict__ iw0,
    const float* __restrict__ isig0,const float* __restrict__ imu0,
    const float* __restrict__ ierev0,
    float4* __restrict__ pack0, float4* __restrict__ packi1,
    float4* __restrict__ pack1,
    float* __restrict__ in_num, float* __restrict__ in_den)
{
    __shared__ float xs[IN];
    if (blockIdx.x < NPACKBLK) {
        const int t = blockIdx.x * 256 + threadIdx.x;
        constexpr int N0 = H0 * H0;          // 36864
        constexpr int N1 = H0 * H1;          // 12288
        if (t < N0) {
            const float wv = fmaxf(w0[t], 0.0f);
            pack0[t] = make_float4(wv, sig0[t] * L2E, sig0[t] * mu0[t] * L2E,
                                   wv * erev0[t]);
        } else if (t < N0 + N1) {
            const int u = t - N0;
            const float wv = fmaxf(iw1[u], 0.0f);
            packi1[u] = make_float4(wv, isig1[u] * L2E,
                                    isig1[u] * imu1[u] * L2E, wv * ierev1[u]);
        } else {
            const int u = t - N0 - N1;
            const float wv = fmaxf(w1[u], 0.0f);
            pack1[u] = make_float4(wv, sig1[u] * L2E, sig1[u] * mu1[u] * L2E,
                                   wv * erev1[u]);
        }
    } else {
        const int b = blockIdx.x - NPACKBLK;
        const int h = threadIdx.x;
        if (h < IN) xs[h] = x[b * IN + h];
        __syncthreads();
        if (h < H0) {
            float num = 0.0f, den = 0.0f;
            #pragma unroll 4
            for (int i = 0; i < IN; ++i) {
                const int idx = i * H0 + h;
                const float wv = fmaxf(iw0[idx], 0.0f);
                const float t  = isig0[idx] * L2E * (imu0[idx] - xs[i]);
                const float a  = wv * sig_from_t(t);
                num = fmaf(a, ierev0[idx], num);
                den += a;
            }
            in_num[b * H0 + h] = num;
            in_den[b * H0 + h] = den;
        }
    }
}

// ---------------------------------------------------------------------------
// Layer-0 sweep body: LEN i-values x 4 rows (paired), compile-time trip count.
template <int LEN>
static __device__ __forceinline__ void sweep0_body(
    const float4* __restrict__ pp,      // pack0 + ibase*H0 + h
    const float* vsbase, int ibase,     // &vs[0][0]
    v2f& n01, v2f& d01, v2f& n23, v2f& d23)
{
    #pragma unroll 8
    for (int ii = 0; ii < LEN; ++ii) {
        const float4 p  = pp[(size_t)ii * H0];        // {wv, sig', smu', wv*er}
        const float4 vv = *(const float4*)(vsbase + (ibase + ii) * 4);
        rows4pk(p, vv, n01, d01, n23, d23);
    }
}

// ---------------------------------------------------------------------------
// Fused unfold + output: 256 blocks x 960 threads (15 waves, one block/CU).
// This is the R10 structure (best measured: 73.5 us) with the fused-rcp
// rows4pk. Session constraints: blockDim <= 1024 (R11 silent fail at 1152);
// no multi-block/CU co-scheduling (R4); working sets past ~84 VGPR spill
// regardless of launch-bounds hints (R6-R9); micro-balancing the split
// regressed (R12) — so config is frozen at R10's.
__global__ __launch_bounds__(960) void fused_unfold_kernel(
    const float* __restrict__ particles,  // [BK, 256]
    const float* __restrict__ noise0,     // [UNF, BK, H0]
    const float* __restrict__ noise1,     // [UNF, BK, H1]
    const float* __restrict__ log_weights,// [B, K]
    const float* __restrict__ gleak0, const float* __restrict__ vleak0,
    const float* __restrict__ cm0,    const float* __restrict__ gdiff0,
    const float* __restrict__ gleak1, const float* __restrict__ vleak1,
    const float* __restrict__ cm1,    const float* __restrict__ gdiff1,
    const float4* __restrict__ pack0,     // [H0*H0]
    const float4* __restrict__ packi1,    // [H0*H1]
    const float4* __restrict__ pack1,     // [H1*H1]
    const float* __restrict__ in_num,     // [B, H0]
    const float* __restrict__ in_den,
    float* __restrict__ outp,             // new_particles region: [BK, 256]
    float* __restrict__ out_y,            // [B, H1] — pre-zeroed
    float* __restrict__ out_lw)           // [B, K]
{
    const int tid = threadIdx.x;
    const int h   = tid % H0;             // 0..191
    const int q   = tid / H0;             // 0..4 (i-split group; q<4 also row)
    const int bk0 = blockIdx.x * 4;
    const int b   = blockIdx.x >> 4;      // batch (16 blocks per batch)
    const int k0  = (blockIdx.x & 15) * 4;// this block's first k within batch

    const int h1  = tid & 63;
    const int qq  = tid >> 6;             // wave id 0..14

    __shared__ __align__(16) float vs[H0][4];     // s0 state, [i][m]
    __shared__ float2 part0[5][4][H0];            // [q][m][h] {num,den}
    __shared__ __align__(16) float v1s[H1][4];    // s1 state, [i][m]
    __shared__ float2 part1[8][4][H1];            // [qq][m][h1]
    __shared__ float  w4[4];                      // softmax weights, this block

    // ---- Softmax weights + log_weights passthrough (wave 0) ----
    if (tid < 64) {
        const float lw = log_weights[b * K + tid];
        out_lw[b * K + tid] = lw;                 // 16x redundant, same value
        float mx = lw;
        #pragma unroll
        for (int o = 32; o > 0; o >>= 1) mx = fmaxf(mx, __shfl_xor(mx, o));
        const float e = __expf(lw - mx);
        float ssum = e;
        #pragma unroll
        for (int o = 32; o > 0; o >>= 1) ssum += __shfl_xor(ssum, o);
        if (tid >= k0 && tid < k0 + 4) w4[tid - k0] = e / ssum;
    }

    // ---- Early layer-1 state loads (hidden behind layer-0 compute) ----
    float nz1[UNF];
    if (tid < 256) {                      // qq in 0..3 = row
        v1s[h1][qq] = particles[(bk0 + qq) * 256 + H0 + h1];
        #pragma unroll
        for (int s = 0; s < UNF; ++s)
            nz1[s] = noise1[s * (BK * H1) + (bk0 + qq) * H1 + h1];
    }

    // ---- Layer 0 setup ----
    float nz[UNF];
    if (q < 4) {
        vs[h][q] = particles[(bk0 + q) * 256 + h];
        #pragma unroll
        for (int s = 0; s < UNF; ++s)
            nz[s] = noise0[s * (BK * H0) + (bk0 + q) * H0 + h];
    }

    const float gl    = fmaxf(gleak0[h], 0.0f);
    const float glvl  = gl * vleak0[h];
    const float cinv  = rcpf(fmaxf(cm0[h], 0.0f) + EPS);
    const float gd    = gdiff0[h] * sqrtf(DT);
    const float innum = in_num[b * H0 + h];
    const float inden = in_den[b * H0 + h];
    __syncthreads();

    // ---- Layer 0 unfold ----
    const int ibase = (q == 4) ? 160 : 40 * q;
    const float4* pp = pack0 + (size_t)ibase * H0 + h;
    const float* vsbase = &vs[0][0];
    for (int step = 0; step < UNF; ++step) {
        v2f n01 = {0.f, 0.f}, d01 = {0.f, 0.f};
        v2f n23 = {0.f, 0.f}, d23 = {0.f, 0.f};
        if (q == 4) sweep0_body<32>(pp, vsbase, ibase, n01, d01, n23, d23);
        else        sweep0_body<40>(pp, vsbase, ibase, n01, d01, n23, d23);
        part0[q][0][h] = make_float2(n01.x, d01.x);
        part0[q][1][h] = make_float2(n01.y, d01.y);
        part0[q][2][h] = make_float2(n23.x, d23.x);
        part0[q][3][h] = make_float2(n23.y, d23.y);
        __syncthreads();
        if (q < 4) {                      // thread (q,h) updates row q
            float tn = innum, td = inden;
            #pragma unroll
            for (int j = 0; j < 5; ++j) {
                const float2 t = part0[j][q][h];
                tn += t.x; td += t.y;
            }
            const float vh = vs[h][q];
            const float d  = (glvl + tn - (gl + td) * vh) * cinv;
            vs[h][q] = fmaf(gd, nz[step], fmaf(d, DT, vh));
        }
        __syncthreads();
    }

    // s0 -> new_particles[:, :H0] (own value; no barrier needed)
    if (q < 4) outp[(bk0 + q) * 256 + h] = vs[h][q];

    // ---- Layer 1 (same 4 rows; s0 in LDS) ----
    float gl1 = 0.f, glvl1 = 0.f, cinv1 = 0.f, gd1 = 0.f;
    v2f i1n01 = {0.f, 0.f}, i1d01 = {0.f, 0.f};
    v2f i1n23 = {0.f, 0.f}, i1d23 = {0.f, 0.f};
    if (tid < 512) {                      // waves 0..7: i-split over 192
        gl1   = fmaxf(gleak1[h1], 0.0f);
        glvl1 = gl1 * vleak1[h1];
        cinv1 = rcpf(fmaxf(cm1[h1], 0.0f) + EPS);
        gd1   = gdiff1[h1] * sqrtf(DT);
        #pragma unroll 4
        for (int ii = 0; ii < 24; ++ii) {
            const int i = qq * 24 + ii;
            const float4 p  = packi1[i * H1 + h1];
            const float4 vv = *(const float4*)(vsbase + i * 4);
            rows4pk(p, vv, i1n01, i1d01, i1n23, i1d23);
        }
    }
    __syncthreads();   // v1s visible

    for (int step = 0; step < UNF; ++step) {
        if (tid < 512) {
            v2f n01 = i1n01, d01 = i1d01, n23 = i1n23, d23 = i1d23;
            #pragma unroll
            for (int ii = 0; ii < 8; ++ii) {
                const int i = qq * 8 + ii;
                const float4 p  = pack1[i * H1 + h1];
                const float4 vv = *(const float4*)&v1s[i][0];
                rows4pk(p, vv, n01, d01, n23, d23);
            }
            part1[qq][0][h1] = make_float2(n01.x, d01.x);
            part1[qq][1][h1] = make_float2(n01.y, d01.y);
            part1[qq][2][h1] = make_float2(n23.x, d23.x);
            part1[qq][3][h1] = make_float2(n23.y, d23.y);
        }
        __syncthreads();
        if (tid < 256) {                  // row qq, element h1
            float tn = 0.f, td = 0.f;
            #pragma unroll
            for (int j = 0; j < 8; ++j) {
                const float2 t = part1[j][qq][h1];
                tn += t.x; td += t.y;
            }
            const float vh = v1s[h1][qq];
            const float d  = (glvl1 + tn - (gl1 + td) * vh) * cinv1;
            v1s[h1][qq] = fmaf(gd1, nz1[step], fmaf(d, DT, vh));
        }
        __syncthreads();
    }

    if (tid < 256)
        outp[(bk0 + qq) * 256 + H0 + h1] = v1s[h1][qq];  // s1 -> [:, H0:]

    // ---- Weighted-mean contribution of this block's 4 particles ----
    if (tid < 64) {
        const float acc = w4[0] * v1s[tid][0] + w4[1] * v1s[tid][1]
                        + w4[2] * v1s[tid][2] + w4[3] * v1s[tid][3];
        atomicAdd(&out_y[b * H1 + tid], acc);
    }
}

// ---------------------------------------------------------------------------
extern "C" void kernel_launch(void* const* d_in, const int* in_sizes, int n_in,
                              void* d_out, int out_size, void* d_ws, size_t ws_size,
                              hipStream_t stream) {
    const float* x           = (const float*)d_in[0];
    const float* particles   = (const float*)d_in[1];
    const float* log_weights = (const float*)d_in[2];
    const float* noise0      = (const float*)d_in[3];
    const float* noise1      = (const float*)d_in[4];
    const float* gleak0 = (const float*)d_in[5];
    const float* vleak0 = (const float*)d_in[6];
    const float* cm0    = (const float*)d_in[7];
    const float* iw0    = (const float*)d_in[8];
    const float* isig0  = (const float*)d_in[9];
    const float* imu0   = (const float*)d_in[10];
    const float* ierev0 = (const float*)d_in[11];
    const float* w0     = (const float*)d_in[12];
    const float* sig0   = (const float*)d_in[13];
    const float* mu0    = (const float*)d_in[14];
    const float* erev0  = (const float*)d_in[15];
    const float* gdiff0 = (const float*)d_in[16];
    const float* gleak1 = (const float*)d_in[17];
    const float* vleak1 = (const float*)d_in[18];
    const float* cm1    = (const float*)d_in[19];
    const float* iw1    = (const float*)d_in[20];
    const float* isig1  = (const float*)d_in[21];
    const float* imu1   = (const float*)d_in[22];
    const float* ierev1 = (const float*)d_in[23];
    const float* w1     = (const float*)d_in[24];
    const float* sig1   = (const float*)d_in[25];
    const float* mu1    = (const float*)d_in[26];
    const float* erev1  = (const float*)d_in[27];
    const float* gdiff1 = (const float*)d_in[28];

    float* out    = (float*)d_out;
    float* out_y  = out;                       // [B, H1] = 1024
    float* out_np = out + B * H1;              // [BK, 256] = 262144
    float* out_lw = out + B * H1 + BK * 256;   // [B, K]   = 1024

    // Workspace layout (floats): pack0 | packi1 | pack1 | in_num0 | in_den0
    float* ws      = (float*)d_ws;
    float4* pack0  = (float4*)(ws);                       // 36864 float4
    float4* packi1 = (float4*)(ws + 4 * 36864);           // 12288 float4
    float4* pack1  = (float4*)(ws + 4 * (36864 + 12288)); //  4096 float4
    float*  in_num0 = ws + 4 * (36864 + 12288 + 4096);    // [B, H0]
    float*  in_den0 = in_num0 + B * H0;                   // [B, H0]

    // out_y accumulated via atomics — zero it (d_out is poisoned pre-call).
    hipMemsetAsync(out_y, 0, B * H1 * sizeof(float), stream);

    prep_kernel<<<NPACKBLK + B, 256, 0, stream>>>(
        w0, sig0, mu0, erev0, iw1, isig1, imu1, ierev1, w1, sig1, mu1, erev1,
        x, iw0, isig0, imu0, ierev0,
        pack0, packi1, pack1, in_num0, in_den0);

    fused_unfold_kernel<<<BK / 4, 960, 0, stream>>>(
        particles, noise0, noise1, log_weights,
        gleak0, vleak0, cm0, gdiff0,
        gleak1, vleak1, cm1, gdiff1,
        pack0, packi1, pack1, in_num0, in_den0,
        out_np, out_y, out_lw);
}

// Round 14
// 194.762 us; speedup vs baseline: 1.0422x; 1.0422x over previous
//
#include <hip/hip_runtime.h>
#include <math.h>

// Problem dims
constexpr int B   = 16;
constexpr int K   = 64;
constexpr int BK  = B * K;        // 1024
constexpr int IN  = 128;
constexpr int H0  = 192;
constexpr int H1  = 64;
constexpr int UNF = 6;
constexpr float EPS = 1e-8f;
constexpr float DT  = 1.0f / 6.0f;
constexpr float L2E = 1.4426950408889634f;   // log2(e)

typedef float v2f __attribute__((ext_vector_type(2)));

static __device__ __forceinline__ float rcpf(float x) {
    return __builtin_amdgcn_rcpf(x);
}
static __device__ __forceinline__ float exp2_fast(float x) {
#if __has_builtin(__builtin_amdgcn_exp2f)
    return __builtin_amdgcn_exp2f(x);   // v_exp_f32
#else
    return exp2f(x);
#endif
}
// sigmoid(z) with z pre-scaled by log2(e): s = 1/(1+2^(-z2)); t = -z2
static __device__ __forceinline__ float sig_from_t(float t) {
    return rcpf(1.0f + exp2_fast(t));
}

// 4 rows of sigmoid-synapse accumulate for one (i,h) pack element, with rows
// paired as v2f so the 12 fma/add ops become 6 v_pk_{fma,add}_f32 (splat
// operands via op_sel — no extra movs). Trans (exp2/rcp) stay scalar: 8.
// NOTE (R13): do NOT fuse the rcp pair — the cross-element swizzle breaks
// pk formation and regressed 73.5 -> 83.6 us.
static __device__ __forceinline__ void rows4pk(const float4 p, const float4 vv,
                                               v2f& n01, v2f& d01,
                                               v2f& n23, v2f& d23) {
    v2f v01; v01.x = vv.x; v01.y = vv.y;
    v2f v23; v23.x = vv.z; v23.y = vv.w;
    const v2f t01 = p.z - p.y * v01;          // v_pk_fma_f32
    const v2f t23 = p.z - p.y * v23;
    v2f e01, e23;
    e01.x = exp2_fast(t01.x); e01.y = exp2_fast(t01.y);
    e23.x = exp2_fast(t23.x); e23.y = exp2_fast(t23.y);
    const v2f o01 = e01 + 1.0f;               // v_pk_add_f32
    const v2f o23 = e23 + 1.0f;
    v2f s01, s23;
    s01.x = rcpf(o01.x); s01.y = rcpf(o01.y);
    s23.x = rcpf(o23.x); s23.y = rcpf(o23.y);
    n01 += s01 * p.w;  d01 += s01 * p.x;      // v_pk_fma_f32 (splat)
    n23 += s23 * p.w;  d23 += s23 * p.x;
}

// ---------------------------------------------------------------------------
// Prep: (a) pack {relu(w), sig*L2E, sig*mu*L2E, relu(w)*erev} into float4 for
// the three hot matrices; (b) layer-0 input synapse sums [B,H0] (x is shared
// by all K particles and all 6 steps). One kernel, branch on blockIdx.
constexpr int NPACK    = H0 * H0 + H0 * H1 + H1 * H1;  // 53248
constexpr int NPACKBLK = NPACK / 256;                   // 208
__global__ __launch_bounds__(256) void prep_kernel(
    const float* __restrict__ w0,  const float* __restrict__ sig0,
    const float* __restrict__ mu0, const float* __restrict__ erev0,
    const float* __restrict__ iw1, const float* __restrict__ isig1,
    const float* __restrict__ imu1,const float* __restrict__ ierev1,
    const float* __restrict__ w1,  const float* __restrict__ sig1,
    const float* __restrict__ mu1, const float* __restrict__ erev1,
    const float* __restrict__ x,   const float* __restrict__ iw0,
    const float* __restrict__ isig0,const float* __restrict__ imu0,
    const float* __restrict__ ierev0,
    float4* __restrict__ pack0, float4* __restrict__ packi1,
    float4* __restrict__ pack1,
    float* __restrict__ in_num, float* __restrict__ in_den)
{
    __shared__ float xs[IN];
    if (blockIdx.x < NPACKBLK) {
        const int t = blockIdx.x * 256 + threadIdx.x;
        constexpr int N0 = H0 * H0;          // 36864
        constexpr int N1 = H0 * H1;          // 12288
        if (t < N0) {
            const float wv = fmaxf(w0[t], 0.0f);
            pack0[t] = make_float4(wv, sig0[t] * L2E, sig0[t] * mu0[t] * L2E,
                                   wv * erev0[t]);
        } else if (t < N0 + N1) {
            const int u = t - N0;
            const float wv = fmaxf(iw1[u], 0.0f);
            packi1[u] = make_float4(wv, isig1[u] * L2E,
                                    isig1[u] * imu1[u] * L2E, wv * ierev1[u]);
        } else {
            const int u = t - N0 - N1;
            const float wv = fmaxf(w1[u], 0.0f);
            pack1[u] = make_float4(wv, sig1[u] * L2E, sig1[u] * mu1[u] * L2E,
                                   wv * erev1[u]);
        }
    } else {
        const int b = blockIdx.x - NPACKBLK;
        const int h = threadIdx.x;
        if (h < IN) xs[h] = x[b * IN + h];
        __syncthreads();
        if (h < H0) {
            float num = 0.0f, den = 0.0f;
            #pragma unroll 4
            for (int i = 0; i < IN; ++i) {
                const int idx = i * H0 + h;
                const float wv = fmaxf(iw0[idx], 0.0f);
                const float t  = isig0[idx] * L2E * (imu0[idx] - xs[i]);
                const float a  = wv * sig_from_t(t);
                num = fmaf(a, ierev0[idx], num);
                den += a;
            }
            in_num[b * H0 + h] = num;
            in_den[b * H0 + h] = den;
        }
    }
}

// ---------------------------------------------------------------------------
// Fused unfold + output: 256 blocks x 960 threads (15 waves, one block/CU).
// Frozen at the session's measured optimum (R10: 73.5 us fused). Session
// constraints that bound this design: blockDim <= 1024 (R11: 1152 silently
// fails); HW does not co-schedule a second large block per CU (R4); working
// sets past the ~84-VGPR allocator target spill to scratch regardless of
// launch-bounds/waves_per_eu hints (R6-R9); split micro-balancing regresses
// via code-size (R12); rcp-pair fusion regresses via broken pk formation
// (R13); 4-row sharing is required to stay under L2 bandwidth.
//
// Layer 0: subgroup q in 0..4 (192 thr each) handles i-range {40,40,40,40,32}
// for ALL 4 rows; state transposed vs[i][4] (one wave-uniform ds_read_b128 =
// all 4 rows); rows paired for v_pk_fma_f32. Partials via LDS; q<4 threads
// apply row q's update.
// Layer 1: waves 0..7 split i 8-ways with the same pairing.
// Output: per-block softmax over the batch's 64 log-weights, atomicAdd of
// this block's 4-row contribution into out_y (zeroed by hipMemsetAsync).
__global__ __launch_bounds__(960) void fused_unfold_kernel(
    const float* __restrict__ particles,  // [BK, 256]
    const float* __restrict__ noise0,     // [UNF, BK, H0]
    const float* __restrict__ noise1,     // [UNF, BK, H1]
    const float* __restrict__ log_weights,// [B, K]
    const float* __restrict__ gleak0, const float* __restrict__ vleak0,
    const float* __restrict__ cm0,    const float* __restrict__ gdiff0,
    const float* __restrict__ gleak1, const float* __restrict__ vleak1,
    const float* __restrict__ cm1,    const float* __restrict__ gdiff1,
    const float4* __restrict__ pack0,     // [H0*H0]
    const float4* __restrict__ packi1,    // [H0*H1]
    const float4* __restrict__ pack1,     // [H1*H1]
    const float* __restrict__ in_num,     // [B, H0]
    const float* __restrict__ in_den,
    float* __restrict__ outp,             // new_particles region: [BK, 256]
    float* __restrict__ out_y,            // [B, H1] — pre-zeroed
    float* __restrict__ out_lw)           // [B, K]
{
    const int tid = threadIdx.x;
    const int h   = tid % H0;             // 0..191
    const int q   = tid / H0;             // 0..4 (i-split group; q<4 also row)
    const int bk0 = blockIdx.x * 4;
    const int b   = blockIdx.x >> 4;      // batch (16 blocks per batch)
    const int k0  = (blockIdx.x & 15) * 4;// this block's first k within batch

    const int h1  = tid & 63;
    const int qq  = tid >> 6;             // wave id 0..14

    __shared__ __align__(16) float vs[H0][4];     // s0 state, [i][m]
    __shared__ float2 part0[5][4][H0];            // [q][m][h] {num,den}
    __shared__ __align__(16) float v1s[H1][4];    // s1 state, [i][m]
    __shared__ float2 part1[8][4][H1];            // [qq][m][h1]
    __shared__ float  w4[4];                      // softmax weights, this block

    // ---- Softmax weights + log_weights passthrough (wave 0) ----
    if (tid < 64) {
        const float lw = log_weights[b * K + tid];
        out_lw[b * K + tid] = lw;                 // 16x redundant, same value
        float mx = lw;
        #pragma unroll
        for (int o = 32; o > 0; o >>= 1) mx = fmaxf(mx, __shfl_xor(mx, o));
        const float e = __expf(lw - mx);
        float ssum = e;
        #pragma unroll
        for (int o = 32; o > 0; o >>= 1) ssum += __shfl_xor(ssum, o);
        if (tid >= k0 && tid < k0 + 4) w4[tid - k0] = e / ssum;
    }

    // ---- Early layer-1 state loads (hidden behind layer-0 compute) ----
    float nz1[UNF];
    if (tid < 256) {                      // qq in 0..3 = row
        v1s[h1][qq] = particles[(bk0 + qq) * 256 + H0 + h1];
        #pragma unroll
        for (int s = 0; s < UNF; ++s)
            nz1[s] = noise1[s * (BK * H1) + (bk0 + qq) * H1 + h1];
    }

    // ---- Layer 0 setup ----
    float nz[UNF];
    if (q < 4) {
        vs[h][q] = particles[(bk0 + q) * 256 + h];
        #pragma unroll
        for (int s = 0; s < UNF; ++s)
            nz[s] = noise0[s * (BK * H0) + (bk0 + q) * H0 + h];
    }

    const float gl    = fmaxf(gleak0[h], 0.0f);
    const float glvl  = gl * vleak0[h];
    const float cinv  = rcpf(fmaxf(cm0[h], 0.0f) + EPS);
    const float gd    = gdiff0[h] * sqrtf(DT);
    const float innum = in_num[b * H0 + h];
    const float inden = in_den[b * H0 + h];
    __syncthreads();

    // ---- Layer 0 unfold ----
    const int ibase = (q == 4) ? 160 : 40 * q;
    const float4* pp = pack0 + (size_t)ibase * H0 + h;
    const float* vsbase = &vs[0][0];
    for (int step = 0; step < UNF; ++step) {
        v2f n01 = {0.f, 0.f}, d01 = {0.f, 0.f};
        v2f n23 = {0.f, 0.f}, d23 = {0.f, 0.f};
        if (q == 4) {
            #pragma unroll 8
            for (int ii = 0; ii < 32; ++ii) {
                const float4 p  = pp[(size_t)ii * H0];
                const float4 vv = *(const float4*)(vsbase + (ibase + ii) * 4);
                rows4pk(p, vv, n01, d01, n23, d23);
            }
        } else {
            #pragma unroll 8
            for (int ii = 0; ii < 40; ++ii) {
                const float4 p  = pp[(size_t)ii * H0];
                const float4 vv = *(const float4*)(vsbase + (ibase + ii) * 4);
                rows4pk(p, vv, n01, d01, n23, d23);
            }
        }
        part0[q][0][h] = make_float2(n01.x, d01.x);
        part0[q][1][h] = make_float2(n01.y, d01.y);
        part0[q][2][h] = make_float2(n23.x, d23.x);
        part0[q][3][h] = make_float2(n23.y, d23.y);
        __syncthreads();
        if (q < 4) {                      // thread (q,h) updates row q
            float tn = innum, td = inden;
            #pragma unroll
            for (int j = 0; j < 5; ++j) {
                const float2 t = part0[j][q][h];
                tn += t.x; td += t.y;
            }
            const float vh = vs[h][q];
            const float d  = (glvl + tn - (gl + td) * vh) * cinv;
            vs[h][q] = fmaf(gd, nz[step], fmaf(d, DT, vh));
        }
        __syncthreads();
    }

    // s0 -> new_particles[:, :H0] (own value; no barrier needed)
    if (q < 4) outp[(bk0 + q) * 256 + h] = vs[h][q];

    // ---- Layer 1 (same 4 rows; s0 in LDS) ----
    float gl1 = 0.f, glvl1 = 0.f, cinv1 = 0.f, gd1 = 0.f;
    v2f i1n01 = {0.f, 0.f}, i1d01 = {0.f, 0.f};
    v2f i1n23 = {0.f, 0.f}, i1d23 = {0.f, 0.f};
    if (tid < 512) {                      // waves 0..7: i-split over 192
        gl1   = fmaxf(gleak1[h1], 0.0f);
        glvl1 = gl1 * vleak1[h1];
        cinv1 = rcpf(fmaxf(cm1[h1], 0.0f) + EPS);
        gd1   = gdiff1[h1] * sqrtf(DT);
        #pragma unroll 4
        for (int ii = 0; ii < 24; ++ii) {
            const int i = qq * 24 + ii;
            const float4 p  = packi1[i * H1 + h1];
            const float4 vv = *(const float4*)(vsbase + i * 4);
            rows4pk(p, vv, i1n01, i1d01, i1n23, i1d23);
        }
    }
    __syncthreads();   // v1s visible

    for (int step = 0; step < UNF; ++step) {
        if (tid < 512) {
            v2f n01 = i1n01, d01 = i1d01, n23 = i1n23, d23 = i1d23;
            #pragma unroll
            for (int ii = 0; ii < 8; ++ii) {
                const int i = qq * 8 + ii;
                const float4 p  = pack1[i * H1 + h1];
                const float4 vv = *(const float4*)&v1s[i][0];
                rows4pk(p, vv, n01, d01, n23, d23);
            }
            part1[qq][0][h1] = make_float2(n01.x, d01.x);
            part1[qq][1][h1] = make_float2(n01.y, d01.y);
            part1[qq][2][h1] = make_float2(n23.x, d23.x);
            part1[qq][3][h1] = make_float2(n23.y, d23.y);
        }
        __syncthreads();
        if (tid < 256) {                  // row qq, element h1
            float tn = 0.f, td = 0.f;
            #pragma unroll
            for (int j = 0; j < 8; ++j) {
                const float2 t = part1[j][qq][h1];
                tn += t.x; td += t.y;
            }
            const float vh = v1s[h1][qq];
            const float d  = (glvl1 + tn - (gl1 + td) * vh) * cinv1;
            v1s[h1][qq] = fmaf(gd1, nz1[step], fmaf(d, DT, vh));
        }
        __syncthreads();
    }

    if (tid < 256)
        outp[(bk0 + qq) * 256 + H0 + h1] = v1s[h1][qq];  // s1 -> [:, H0:]

    // ---- Weighted-mean contribution of this block's 4 particles ----
    if (tid < 64) {
        const float acc = w4[0] * v1s[tid][0] + w4[1] * v1s[tid][1]
                        + w4[2] * v1s[tid][2] + w4[3] * v1s[tid][3];
        atomicAdd(&out_y[b * H1 + tid], acc);
    }
}

// ---------------------------------------------------------------------------
extern "C" void kernel_launch(void* const* d_in, const int* in_sizes, int n_in,
                              void* d_out, int out_size, void* d_ws, size_t ws_size,
                              hipStream_t stream) {
    const float* x           = (const float*)d_in[0];
    const float* particles   = (const float*)d_in[1];
    const float* log_weights = (const float*)d_in[2];
    const float* noise0      = (const float*)d_in[3];
    const float* noise1      = (const float*)d_in[4];
    const float* gleak0 = (const float*)d_in[5];
    const float* vleak0 = (const float*)d_in[6];
    const float* cm0    = (const float*)d_in[7];
    const float* iw0    = (const float*)d_in[8];
    const float* isig0  = (const float*)d_in[9];
    const float* imu0   = (const float*)d_in[10];
    const float* ierev0 = (const float*)d_in[11];
    const float* w0     = (const float*)d_in[12];
    const float* sig0   = (const float*)d_in[13];
    const float* mu0    = (const float*)d_in[14];
    const float* erev0  = (const float*)d_in[15];
    const float* gdiff0 = (const float*)d_in[16];
    const float* gleak1 = (const float*)d_in[17];
    const float* vleak1 = (const float*)d_in[18];
    const float* cm1    = (const float*)d_in[19];
    const float* iw1    = (const float*)d_in[20];
    const float* isig1  = (const float*)d_in[21];
    const float* imu1   = (const float*)d_in[22];
    const float* ierev1 = (const float*)d_in[23];
    const float* w1     = (const float*)d_in[24];
    const float* sig1   = (const float*)d_in[25];
    const float* mu1    = (const float*)d_in[26];
    const float* erev1  = (const float*)d_in[27];
    const float* gdiff1 = (const float*)d_in[28];

    float* out    = (float*)d_out;
    float* out_y  = out;                       // [B, H1] = 1024
    float* out_np = out + B * H1;              // [BK, 256] = 262144
    float* out_lw = out + B * H1 + BK * 256;   // [B, K]   = 1024

    // Workspace layout (floats): pack0 | packi1 | pack1 | in_num0 | in_den0
    float* ws      = (float*)d_ws;
    float4* pack0  = (float4*)(ws);                       // 36864 float4
    float4* packi1 = (float4*)(ws + 4 * 36864);           // 12288 float4
    float4* pack1  = (float4*)(ws + 4 * (36864 + 12288)); //  4096 float4
    float*  in_num0 = ws + 4 * (36864 + 12288 + 4096);    // [B, H0]
    float*  in_den0 = in_num0 + B * H0;                   // [B, H0]

    // out_y accumulated via atomics — zero it (d_out is poisoned pre-call).
    hipMemsetAsync(out_y, 0, B * H1 * sizeof(float), stream);

    prep_kernel<<<NPACKBLK + B, 256, 0, stream>>>(
        w0, sig0, mu0, erev0, iw1, isig1, imu1, ierev1, w1, sig1, mu1, erev1,
        x, iw0, isig0, imu0, ierev0,
        pack0, packi1, pack1, in_num0, in_den0);

    fused_unfold_kernel<<<BK / 4, 960, 0, stream>>>(
        particles, noise0, noise1, log_weights,
        gleak0, vleak0, cm0, gdiff0,
        gleak1, vleak1, cm1, gdiff1,
        pack0, packi1, pack1, in_num0, in_den0,
        out_np, out_y, out_lw);
}